// Round 3
// baseline (2019.176 us; speedup 1.0000x reference)
//
#include <hip/hip_runtime.h>

#define TT   512
#define DIN  2048
#define NH1  128
#define NH2  64
#define NF1  32
#define NB   64

__device__ __forceinline__ float tanh_fast(float x) {
    x = fminf(fmaxf(x, -15.0f), 15.0f);
    float e = __expf(2.0f * x);
    return (e - 1.0f) / (e + 1.0f);
}

__device__ __forceinline__ float rlane(float v, int l) {
    return __int_as_float(__builtin_amdgcn_readlane(__float_as_int(v), l));
}

// Barrier WITHOUT vmcnt drain: LDS ordering only. Global loads stay in flight
// across the barrier (the __syncthreads vmcnt(0) drain was killing the scan's
// xp1 prefetch and is unnecessary: cross-wave data only moves through LDS).
#define BAR() asm volatile("s_waitcnt lgkmcnt(0)\n\ts_barrier" ::: "memory")

// ---------------------------------------------------------------------------
// Kernel A: xp1[m][n] = sum_d x[m][d]*W_ih1[n][d] + b_ih1[n] + b_hh1[n]
// M=32768, K=2048, N=128. BM=128, BK=32, **512 threads** (8 waves = 2/SIMD
// for latency hiding — round-2's 256thr/1 wave-per-SIMD was the stall).
// Micro-tile 8(M) x 4(N). ws keeps the 12-stride interleave: b128 read at
// dword 12*(ng>>1)+4*(ng&1) → max 2-way bank aliasing (free, m136).
// ---------------------------------------------------------------------------
__global__ __launch_bounds__(512) void xp1_gemm(const float* __restrict__ x,
                                                const float* __restrict__ Wih1,
                                                const float* __restrict__ bih1,
                                                const float* __restrict__ bhh1,
                                                float* __restrict__ xp1) {
    __shared__ __align__(16) float xs[32][128];   // [k][m]
    __shared__ __align__(16) float ws[32][188];   // [k][n'] n' = 12*(n>>3)+(n&7)

    const int tid = threadIdx.x;
    const int m0  = blockIdx.x * 128;
    const int mg  = tid >> 5;    // 0..15 -> rows mg*8..+7
    const int ng  = tid & 31;    // 0..31 -> cols ng*4..+3

    float bias[4];
#pragma unroll
    for (int j = 0; j < 4; ++j)
        bias[j] = bih1[ng * 4 + j] + bhh1[ng * 4 + j];

    float acc[8][4];
#pragma unroll
    for (int i = 0; i < 8; ++i)
#pragma unroll
        for (int j = 0; j < 4; ++j) acc[i][j] = 0.0f;

    for (int kc = 0; kc < DIN; kc += 32) {
        // stage x tile: 128 rows x 32 k = 1024 float4, 2 per thread
#pragma unroll
        for (int q = 0; q < 2; ++q) {
            int f = tid + q * 512;
            int row = f >> 3, kq = f & 7;
            float4 v = *(const float4*)&x[(size_t)(m0 + row) * DIN + kc + kq * 4];
            xs[kq * 4 + 0][row] = v.x;
            xs[kq * 4 + 1][row] = v.y;
            xs[kq * 4 + 2][row] = v.z;
            xs[kq * 4 + 3][row] = v.w;
        }
        // stage W tile: 128 rows x 32 k, interleaved col map
#pragma unroll
        for (int q = 0; q < 2; ++q) {
            int f = tid + q * 512;
            int row = f >> 3, kq = f & 7;
            int rp = 12 * (row >> 3) + (row & 7);
            float4 v = *(const float4*)&Wih1[(size_t)row * DIN + kc + kq * 4];
            ws[kq * 4 + 0][rp] = v.x;
            ws[kq * 4 + 1][rp] = v.y;
            ws[kq * 4 + 2][rp] = v.z;
            ws[kq * 4 + 3][rp] = v.w;
        }
        __syncthreads();

#pragma unroll 4
        for (int k = 0; k < 32; ++k) {
            float4 a0 = *(const float4*)&xs[k][mg * 8];
            float4 a1 = *(const float4*)&xs[k][mg * 8 + 4];
            float4 bb = *(const float4*)&ws[k][12 * (ng >> 1) + 4 * (ng & 1)];
            float av[8] = {a0.x, a0.y, a0.z, a0.w, a1.x, a1.y, a1.z, a1.w};
            float bv[4] = {bb.x, bb.y, bb.z, bb.w};
#pragma unroll
            for (int i = 0; i < 8; ++i)
#pragma unroll
                for (int j = 0; j < 4; ++j)
                    acc[i][j] = fmaf(av[i], bv[j], acc[i][j]);
        }
        __syncthreads();
    }

#pragma unroll
    for (int i = 0; i < 8; ++i) {
        size_t m = (size_t)(m0 + mg * 8 + i);
        float4 o = make_float4(acc[i][0] + bias[0], acc[i][1] + bias[1],
                               acc[i][2] + bias[2], acc[i][3] + bias[3]);
        *(float4*)&xp1[m * NH1 + ng * 4] = o;
    }
}

// ---------------------------------------------------------------------------
// Kernel B: fused 2-layer scan + FC head. One block (=1 CU) per batch elem.
// 4 waves, one per SIMD.
//   wave0: H1 rows 0-63    wave1: H1 rows 64-127
//     own-half h1 broadcast from OWN registers (readlane of last step's h),
//     other half via one ds_read_b32 issued before 256 cyc of own-half FMAs.
//   wave2: xp2[t] = Wih2 . H1[t] + bias, 1 step behind (parity LDS buffer)
//   wave3: h2 chain fully in registers (readlane), 2 steps behind; FC at end.
// xp1 loads batched 8 steps and issued one group AHEAD; BAR() has no vmcnt
// drain so they stay in flight across barriers.
// ---------------------------------------------------------------------------
__global__ __launch_bounds__(256, 1) void rnn_scan(
        const float* __restrict__ xp1,  const float* __restrict__ Whh1,
        const float* __restrict__ Wih2, const float* __restrict__ Whh2,
        const float* __restrict__ bih2, const float* __restrict__ bhh2,
        const float* __restrict__ Wfc1, const float* __restrict__ bfc1,
        const float* __restrict__ Wfc2, const float* __restrict__ bfc2,
        float* __restrict__ out) {
    __shared__ __align__(16) float h1buf[2][NH1];
    __shared__ __align__(16) float xp2buf[2][NH2];

    const int tid  = threadIdx.x;
    const int lane = tid & 63;
    const int wv   = tid >> 6;
    const int b    = blockIdx.x;

    float wrow[128];
    float b2 = 0.0f;

    if (wv <= 1) {
        const int row = wv * 64 + lane;
        const float4* src = (const float4*)(Whh1 + (size_t)row * NH1);
#pragma unroll
        for (int i = 0; i < 32; ++i) {
            float4 v = src[i];
            wrow[4*i+0] = v.x; wrow[4*i+1] = v.y;
            wrow[4*i+2] = v.z; wrow[4*i+3] = v.w;
        }
    } else if (wv == 2) {
        const float4* src = (const float4*)(Wih2 + (size_t)lane * NH1);
#pragma unroll
        for (int i = 0; i < 32; ++i) {
            float4 v = src[i];
            wrow[4*i+0] = v.x; wrow[4*i+1] = v.y;
            wrow[4*i+2] = v.z; wrow[4*i+3] = v.w;
        }
        b2 = bih2[lane] + bhh2[lane];
    } else {
        const float4* src = (const float4*)(Whh2 + (size_t)lane * NH2);
#pragma unroll
        for (int i = 0; i < 16; ++i) {
            float4 v = src[i];
            wrow[4*i+0] = v.x; wrow[4*i+1] = v.y;
            wrow[4*i+2] = v.z; wrow[4*i+3] = v.w;
        }
    }

    if (tid < 128) h1buf[0][tid] = 0.0f;

    const int  row   = wv * 64 + lane;            // wave0/1 h1 row
    const int  kown  = wv * 64;                   // own-half k base (w0:0, w1:64)
    const int  koth  = 64 - kown;                 // other-half k base
    const float* xprow = xp1 + ((size_t)b * TT) * NH1 + row;

    float xr[8], xrn[8];
    if (wv <= 1) {
#pragma unroll
        for (int j = 0; j < 8; ++j) xr[j] = xprow[(size_t)j * NH1];   // t = 0..7
    }

    __syncthreads();   // one-time init barrier (drains weight loads too)

    float hown   = 0.0f;   // wave0/1: own h1 value from last step
    float h2prev = 0.0f;   // wave3: h2 state (one per lane)

    for (int g = 0; g < 64; ++g) {
        // issue NEXT group's xp1 loads (consumed 8 steps from now)
        if (wv <= 1 && g < 63) {
            const size_t t0 = (size_t)(g + 1) * 8;
#pragma unroll
            for (int j = 0; j < 8; ++j) xrn[j] = xprow[(t0 + j) * NH1];
        }
#pragma unroll
        for (int j = 0; j < 8; ++j) {           // step s = 8g + j + 1, 1..512
            const int s   = 8 * g + j + 1;
            const int cur = j & 1;
            const int nxt = cur ^ 1;
            if (wv <= 1) {
                float hoth = h1buf[cur][koth + lane];   // issue early; used after own half
                float a0 = xr[j], a1 = 0.f, a2 = 0.f, a3 = 0.f;
#pragma unroll
                for (int l = 0; l < 64; l += 4) {       // own half: register broadcast
                    a0 = fmaf(wrow[kown + l],     rlane(hown, l),     a0);
                    a1 = fmaf(wrow[kown + l + 1], rlane(hown, l + 1), a1);
                    a2 = fmaf(wrow[kown + l + 2], rlane(hown, l + 2), a2);
                    a3 = fmaf(wrow[kown + l + 3], rlane(hown, l + 3), a3);
                }
#pragma unroll
                for (int l = 0; l < 64; l += 4) {       // other half: LDS value
                    a0 = fmaf(wrow[koth + l],     rlane(hoth, l),     a0);
                    a1 = fmaf(wrow[koth + l + 1], rlane(hoth, l + 1), a1);
                    a2 = fmaf(wrow[koth + l + 2], rlane(hoth, l + 2), a2);
                    a3 = fmaf(wrow[koth + l + 3], rlane(hoth, l + 3), a3);
                }
                float hv = tanh_fast((a0 + a1) + (a2 + a3));
                h1buf[nxt][row] = hv;
                hown = hv;
            } else if (wv == 2) {
                if (s >= 2) {
                    float2 hh = *(const float2*)&h1buf[cur][2 * lane];  // H1[s-1]
                    float a0 = b2, a1 = 0.f, a2 = 0.f, a3 = 0.f;
#pragma unroll
                    for (int l = 0; l < 64; l += 2) {
                        float he0 = rlane(hh.x, l),     ho0 = rlane(hh.y, l);
                        float he1 = rlane(hh.x, l + 1), ho1 = rlane(hh.y, l + 1);
                        a0 = fmaf(wrow[2*l],     he0, a0);
                        a1 = fmaf(wrow[2*l + 1], ho0, a1);
                        a2 = fmaf(wrow[2*l + 2], he1, a2);
                        a3 = fmaf(wrow[2*l + 3], ho1, a3);
                    }
                    xp2buf[j & 1][lane] = (a0 + a1) + (a2 + a3);  // xp2[s-1]+bias
                }
            } else {
                if (s >= 3) {
                    float xv = xp2buf[(j + 1) & 1][lane];   // xp2[s-2] + bias
                    float a0 = 0.f, a1 = 0.f, a2 = 0.f, a3 = 0.f;
#pragma unroll
                    for (int l = 0; l < 64; l += 4) {
                        a0 = fmaf(wrow[l],     rlane(h2prev, l),     a0);
                        a1 = fmaf(wrow[l + 1], rlane(h2prev, l + 1), a1);
                        a2 = fmaf(wrow[l + 2], rlane(h2prev, l + 2), a2);
                        a3 = fmaf(wrow[l + 3], rlane(h2prev, l + 3), a3);
                    }
                    h2prev = tanh_fast(xv + ((a0 + a1) + (a2 + a3)));  // h2[s-2]
                }
            }
            BAR();
        }
        if (wv <= 1 && g < 63) {
#pragma unroll
            for (int j = 0; j < 8; ++j) xr[j] = xrn[j];
        }
    }

    // tail step s = 513: wave2 makes xp2[512]; wave3 makes h2[511]
    {
        if (wv == 2) {
            float2 hh = *(const float2*)&h1buf[0][2 * lane];   // H1[512]
            float a0 = b2, a1 = 0.f, a2 = 0.f, a3 = 0.f;
#pragma unroll
            for (int l = 0; l < 64; l += 2) {
                float he0 = rlane(hh.x, l),     ho0 = rlane(hh.y, l);
                float he1 = rlane(hh.x, l + 1), ho1 = rlane(hh.y, l + 1);
                a0 = fmaf(wrow[2*l],     he0, a0);
                a1 = fmaf(wrow[2*l + 1], ho0, a1);
                a2 = fmaf(wrow[2*l + 2], he1, a2);
                a3 = fmaf(wrow[2*l + 3], ho1, a3);
            }
            xp2buf[0][lane] = (a0 + a1) + (a2 + a3);           // xp2[512]+bias
        } else if (wv == 3) {
            float xv = xp2buf[1][lane];                        // xp2[511]+bias
            float a0 = 0.f, a1 = 0.f, a2 = 0.f, a3 = 0.f;
#pragma unroll
            for (int l = 0; l < 64; l += 4) {
                a0 = fmaf(wrow[l],     rlane(h2prev, l),     a0);
                a1 = fmaf(wrow[l + 1], rlane(h2prev, l + 1), a1);
                a2 = fmaf(wrow[l + 2], rlane(h2prev, l + 2), a2);
                a3 = fmaf(wrow[l + 3], rlane(h2prev, l + 3), a3);
            }
            h2prev = tanh_fast(xv + ((a0 + a1) + (a2 + a3)));  // h2[511]
        }
        BAR();
    }
    // tail step s = 514: wave3 makes h2[512]; then FC head (wave3 only)
    if (wv == 3) {
        float xv = xp2buf[0][lane];                            // xp2[512]+bias
        float a0 = 0.f, a1 = 0.f, a2 = 0.f, a3 = 0.f;
#pragma unroll
        for (int l = 0; l < 64; l += 4) {
            a0 = fmaf(wrow[l],     rlane(h2prev, l),     a0);
            a1 = fmaf(wrow[l + 1], rlane(h2prev, l + 1), a1);
            a2 = fmaf(wrow[l + 2], rlane(h2prev, l + 2), a2);
            a3 = fmaf(wrow[l + 3], rlane(h2prev, l + 3), a3);
        }
        h2prev = tanh_fast(xv + ((a0 + a1) + (a2 + a3)));      // H2[512]

        // FC head: load Wfc1 AFTER the loop (keeps loop register pressure low)
        float wfc[64];
        const int fr = lane & 31;
        const float4* fsrc = (const float4*)(Wfc1 + (size_t)fr * NH2);
#pragma unroll
        for (int i = 0; i < 16; ++i) {
            float4 v = fsrc[i];
            wfc[4*i+0] = v.x; wfc[4*i+1] = v.y;
            wfc[4*i+2] = v.z; wfc[4*i+3] = v.w;
        }
        float a = (lane < 32) ? bfc1[lane] : 0.0f;
#pragma unroll
        for (int k = 0; k < 64; ++k)
            a = fmaf(wfc[k], rlane(h2prev, k), a);
        float v = (lane < 32) ? fmaxf(a, 0.0f) * Wfc2[lane] : 0.0f;
#pragma unroll
        for (int off = 16; off > 0; off >>= 1) v += __shfl_down(v, off);
        if (lane == 0) out[b] = v + bfc2[0];
    }
}

extern "C" void kernel_launch(void* const* d_in, const int* in_sizes, int n_in,
                              void* d_out, int out_size, void* d_ws, size_t ws_size,
                              hipStream_t stream) {
    const float* x     = (const float*)d_in[0];
    const float* Wih1  = (const float*)d_in[1];
    const float* Whh1  = (const float*)d_in[2];
    const float* bih1  = (const float*)d_in[3];
    const float* bhh1  = (const float*)d_in[4];
    const float* Wih2  = (const float*)d_in[5];
    const float* Whh2  = (const float*)d_in[6];
    const float* bih2  = (const float*)d_in[7];
    const float* bhh2  = (const float*)d_in[8];
    const float* Wfc1  = (const float*)d_in[9];
    const float* bfc1  = (const float*)d_in[10];
    const float* Wfc2  = (const float*)d_in[11];
    const float* bfc2  = (const float*)d_in[12];
    float* outp = (float*)d_out;

    float* xp1 = (float*)d_ws;   // 32768 x 128 fp32 = 16 MB

    xp1_gemm<<<dim3((NB * TT) / 128), dim3(512), 0, stream>>>(x, Wih1, bih1, bhh1, xp1);
    rnn_scan<<<dim3(NB), dim3(256), 0, stream>>>(xp1, Whh1, Wih2, Whh2, bih2, bhh2,
                                                 Wfc1, bfc1, Wfc2, bfc2, outp);
}

// Round 4
// 733.422 us; speedup vs baseline: 2.7531x; 2.7531x over previous
//
#include <hip/hip_runtime.h>

#define TT   512
#define DIN  2048
#define NH1  128
#define NH2  64
#define NB   64

typedef __attribute__((ext_vector_type(8))) __bf16 bf16x8;
typedef __attribute__((ext_vector_type(4))) float f32x4;

__device__ __forceinline__ float tanh_fast(float x) {
    x = fminf(fmaxf(x, -15.0f), 15.0f);
    float e = __expf(2.0f * x);
    return (e - 1.0f) / (e + 1.0f);
}

__device__ __forceinline__ float rlane(float v, int l) {
    return __int_as_float(__builtin_amdgcn_readlane(__float_as_int(v), l));
}

// Barrier WITHOUT vmcnt drain: LDS ordering only. Global loads stay in flight.
#define BAR() asm volatile("s_waitcnt lgkmcnt(0)\n\ts_barrier" ::: "memory")

// ---------------------------------------------------------------------------
// Kernel A: xp1 = x @ W_ih1^T + b  via 3-term bf16-split MFMA (~fp32 precision)
//   x = xhi + xlo (bf16 split), W likewise; x*W ~= xhi*whi + xlo*whi + xhi*wlo
// M=32768, K=2048, N=128. Block 128(M)x128(N), 4 waves, wave tile 32x128.
// x: global -> registers DIRECTLY in A-frag layout (no LDS, no x barriers).
//    lane reads x[m0+ms*16+(lane&15)][kc+quad*8 .. +7]  (8 consecutive fp32).
// W: staged once per chunk to LDS as hi/lo bf16 planes (1 MB total, L2-hot).
// Register prefetch of chunk k+1 issued before chunk-k MFMAs -> latency hidden.
// ---------------------------------------------------------------------------
__global__ __launch_bounds__(256, 1) void xp1_gemm(const float* __restrict__ x,
                                                   const float* __restrict__ W,
                                                   const float* __restrict__ bih1,
                                                   const float* __restrict__ bhh1,
                                                   float* __restrict__ xp1) {
    __shared__ __align__(16) __bf16 wl[2][NH1][40];   // [plane][n][k pad 40]

    const int tid  = threadIdx.x;
    const int lane = tid & 63;
    const int wv   = tid >> 6;
    const int quad = lane >> 4;
    const int l16  = lane & 15;
    const int m0   = blockIdx.x * 128 + wv * 32;

    const int wr = tid >> 1;         // W stage: row
    const int wk = (tid & 1) * 16;   // W stage: k offset (16 fp32 per thread)

    float bias[8];
#pragma unroll
    for (int nt = 0; nt < 8; ++nt)
        bias[nt] = bih1[nt * 16 + l16] + bhh1[nt * 16 + l16];

    f32x4 acc[2][8];
#pragma unroll
    for (int ms = 0; ms < 2; ++ms)
#pragma unroll
        for (int nt = 0; nt < 8; ++nt)
            acc[ms][nt] = (f32x4){0.f, 0.f, 0.f, 0.f};

    const float* xr0 = x + (size_t)(m0 + l16) * DIN + quad * 8;
    const float* xr1 = x + (size_t)(m0 + 16 + l16) * DIN + quad * 8;
    const float* wp  = W + (size_t)wr * DIN + wk;

    // preload chunk 0
    float4 xa0 = *(const float4*)(xr0);
    float4 xb0 = *(const float4*)(xr0 + 4);
    float4 xa1 = *(const float4*)(xr1);
    float4 xb1 = *(const float4*)(xr1 + 4);
    float4 w0  = *(const float4*)(wp);
    float4 w1  = *(const float4*)(wp + 4);
    float4 w2  = *(const float4*)(wp + 8);
    float4 w3  = *(const float4*)(wp + 12);

    for (int kc = 0; kc < DIN; kc += 32) {
        // ---- convert & store W hi/lo planes (vmcnt wait auto-inserted)
        {
            float wf[16] = {w0.x, w0.y, w0.z, w0.w, w1.x, w1.y, w1.z, w1.w,
                            w2.x, w2.y, w2.z, w2.w, w3.x, w3.y, w3.z, w3.w};
            bf16x8 hv0, lv0, hv1, lv1;
#pragma unroll
            for (int j = 0; j < 8; ++j) {
                __bf16 h = (__bf16)wf[j];
                hv0[j] = h;
                lv0[j] = (__bf16)(wf[j] - (float)h);
            }
#pragma unroll
            for (int j = 0; j < 8; ++j) {
                __bf16 h = (__bf16)wf[8 + j];
                hv1[j] = h;
                lv1[j] = (__bf16)(wf[8 + j] - (float)h);
            }
            *(bf16x8*)&wl[0][wr][wk]     = hv0;
            *(bf16x8*)&wl[0][wr][wk + 8] = hv1;
            *(bf16x8*)&wl[1][wr][wk]     = lv0;
            *(bf16x8*)&wl[1][wr][wk + 8] = lv1;
        }
        BAR();

        // ---- convert current x to A-frags (before regs are overwritten)
        bf16x8 ah0, al0, ah1, al1;
        {
            float f0[8] = {xa0.x, xa0.y, xa0.z, xa0.w, xb0.x, xb0.y, xb0.z, xb0.w};
            float f1[8] = {xa1.x, xa1.y, xa1.z, xa1.w, xb1.x, xb1.y, xb1.z, xb1.w};
#pragma unroll
            for (int j = 0; j < 8; ++j) {
                __bf16 h0 = (__bf16)f0[j];
                ah0[j] = h0;
                al0[j] = (__bf16)(f0[j] - (float)h0);
                __bf16 h1 = (__bf16)f1[j];
                ah1[j] = h1;
                al1[j] = (__bf16)(f1[j] - (float)h1);
            }
        }

        // ---- prefetch next chunk (stays in flight through the MFMAs)
        if (kc + 32 < DIN) {
            xa0 = *(const float4*)(xr0 + kc + 32);
            xb0 = *(const float4*)(xr0 + kc + 36);
            xa1 = *(const float4*)(xr1 + kc + 32);
            xb1 = *(const float4*)(xr1 + kc + 36);
            w0  = *(const float4*)(wp + kc + 32);
            w1  = *(const float4*)(wp + kc + 36);
            w2  = *(const float4*)(wp + kc + 40);
            w3  = *(const float4*)(wp + kc + 44);
        }

        // ---- B-frags from LDS + 3-term MFMAs
#pragma unroll
        for (int nt = 0; nt < 8; ++nt) {
            bf16x8 bh = *(bf16x8*)&wl[0][nt * 16 + l16][quad * 8];
            bf16x8 bl = *(bf16x8*)&wl[1][nt * 16 + l16][quad * 8];
            acc[0][nt] = __builtin_amdgcn_mfma_f32_16x16x32_bf16(ah0, bh, acc[0][nt], 0, 0, 0);
            acc[0][nt] = __builtin_amdgcn_mfma_f32_16x16x32_bf16(al0, bh, acc[0][nt], 0, 0, 0);
            acc[0][nt] = __builtin_amdgcn_mfma_f32_16x16x32_bf16(ah0, bl, acc[0][nt], 0, 0, 0);
            acc[1][nt] = __builtin_amdgcn_mfma_f32_16x16x32_bf16(ah1, bh, acc[1][nt], 0, 0, 0);
            acc[1][nt] = __builtin_amdgcn_mfma_f32_16x16x32_bf16(al1, bh, acc[1][nt], 0, 0, 0);
            acc[1][nt] = __builtin_amdgcn_mfma_f32_16x16x32_bf16(ah1, bl, acc[1][nt], 0, 0, 0);
        }
        BAR();   // all reads done before next chunk's LDS overwrite
    }

    // ---- epilogue: C/D layout col=lane&15, row=quad*4+reg [m89-verified]
#pragma unroll
    for (int ms = 0; ms < 2; ++ms) {
        const int mb = m0 + ms * 16 + quad * 4;
#pragma unroll
        for (int nt = 0; nt < 8; ++nt) {
#pragma unroll
            for (int r = 0; r < 4; ++r)
                xp1[(size_t)(mb + r) * NH1 + nt * 16 + l16] = acc[ms][nt][r] + bias[nt];
        }
    }
}

// ---------------------------------------------------------------------------
// Kernel B: fused 2-layer scan + FC head. One block per batch elem, 4 waves.
// ALL private-array indices are compile-time constants (round-3's dynamic
// wrow[kown+l] demoted wrow to scratch -> 7 MB spill traffic; fixed by
// storing own-half first: wrow[i] = Whh1row[(kown+i)&127], body uses wrow[l]
// and wrow[64+l]). BAR() = lgkm-only barrier; xp1 prefetch batched 8 steps.
// ---------------------------------------------------------------------------
__global__ __launch_bounds__(256, 1) void rnn_scan(
        const float* __restrict__ xp1,  const float* __restrict__ Whh1,
        const float* __restrict__ Wih2, const float* __restrict__ Whh2,
        const float* __restrict__ bih2, const float* __restrict__ bhh2,
        const float* __restrict__ Wfc1, const float* __restrict__ bfc1,
        const float* __restrict__ Wfc2, const float* __restrict__ bfc2,
        float* __restrict__ out) {
    __shared__ __align__(16) float h1buf[2][NH1];
    __shared__ __align__(16) float xp2buf[2][NH2];

    const int tid  = threadIdx.x;
    const int lane = tid & 63;
    const int wv   = tid >> 6;
    const int b    = blockIdx.x;

    const int kown = wv * 64;        // used only in MEMORY addressing (ok)
    const int koth = 64 - kown;

    float wrow[128];
    float b2 = 0.0f;

    if (wv <= 1) {
        const int row = wv * 64 + lane;
        const float* src = Whh1 + (size_t)row * NH1;
#pragma unroll
        for (int i = 0; i < 128; i += 4) {          // own half first
            float4 v = *(const float4*)&src[(kown + i) & 127];
            wrow[i] = v.x; wrow[i+1] = v.y; wrow[i+2] = v.z; wrow[i+3] = v.w;
        }
    } else if (wv == 2) {
        const float4* src = (const float4*)(Wih2 + (size_t)lane * NH1);
#pragma unroll
        for (int i = 0; i < 32; ++i) {
            float4 v = src[i];
            wrow[4*i+0] = v.x; wrow[4*i+1] = v.y;
            wrow[4*i+2] = v.z; wrow[4*i+3] = v.w;
        }
        b2 = bih2[lane] + bhh2[lane];
    } else {
        const float4* src = (const float4*)(Whh2 + (size_t)lane * NH2);
#pragma unroll
        for (int i = 0; i < 16; ++i) {
            float4 v = src[i];
            wrow[4*i+0] = v.x; wrow[4*i+1] = v.y;
            wrow[4*i+2] = v.z; wrow[4*i+3] = v.w;
        }
    }

    if (tid < 128) h1buf[0][tid] = 0.0f;

    const int row = wv * 64 + lane;
    const float* xprow = xp1 + ((size_t)b * TT) * NH1 + row;

    float xr[8], xrn[8];
    if (wv <= 1) {
#pragma unroll
        for (int j = 0; j < 8; ++j) xr[j] = xprow[(size_t)j * NH1];
    }

    __syncthreads();   // one-time init barrier

    float hown   = 0.0f;   // wave0/1: own h1 value
    float h2prev = 0.0f;   // wave3: h2 state

    for (int g = 0; g < 64; ++g) {
        if (wv <= 1 && g < 63) {
            const size_t t0 = (size_t)(g + 1) * 8;
#pragma unroll
            for (int j = 0; j < 8; ++j) xrn[j] = xprow[(t0 + j) * NH1];
        }
#pragma unroll
        for (int j = 0; j < 8; ++j) {           // step s = 8g + j + 1
            const int s   = 8 * g + j + 1;
            const int cur = j & 1;
            const int nxt = cur ^ 1;
            if (wv <= 1) {
                float hoth = h1buf[cur][koth + lane];   // issued early, used late
                float a0 = xr[j], a1 = 0.f, a2 = 0.f, a3 = 0.f;
#pragma unroll
                for (int l = 0; l < 64; l += 4) {       // own half (registers)
                    a0 = fmaf(wrow[l],     rlane(hown, l),     a0);
                    a1 = fmaf(wrow[l + 1], rlane(hown, l + 1), a1);
                    a2 = fmaf(wrow[l + 2], rlane(hown, l + 2), a2);
                    a3 = fmaf(wrow[l + 3], rlane(hown, l + 3), a3);
                }
#pragma unroll
                for (int l = 0; l < 64; l += 4) {       // other half (LDS value)
                    a0 = fmaf(wrow[64 + l],     rlane(hoth, l),     a0);
                    a1 = fmaf(wrow[64 + l + 1], rlane(hoth, l + 1), a1);
                    a2 = fmaf(wrow[64 + l + 2], rlane(hoth, l + 2), a2);
                    a3 = fmaf(wrow[64 + l + 3], rlane(hoth, l + 3), a3);
                }
                float hv = tanh_fast((a0 + a1) + (a2 + a3));
                h1buf[nxt][row] = hv;
                hown = hv;
            } else if (wv == 2) {
                if (s >= 2) {
                    float2 hh = *(const float2*)&h1buf[cur][2 * lane];  // H1[s-1]
                    float a0 = b2, a1 = 0.f, a2 = 0.f, a3 = 0.f;
#pragma unroll
                    for (int l = 0; l < 64; l += 2) {
                        float he0 = rlane(hh.x, l),     ho0 = rlane(hh.y, l);
                        float he1 = rlane(hh.x, l + 1), ho1 = rlane(hh.y, l + 1);
                        a0 = fmaf(wrow[2*l],     he0, a0);
                        a1 = fmaf(wrow[2*l + 1], ho0, a1);
                        a2 = fmaf(wrow[2*l + 2], he1, a2);
                        a3 = fmaf(wrow[2*l + 3], ho1, a3);
                    }
                    xp2buf[j & 1][lane] = (a0 + a1) + (a2 + a3);  // xp2[s-1]+bias
                }
            } else {
                if (s >= 3) {
                    float xv = xp2buf[(j + 1) & 1][lane];   // xp2[s-2]+bias
                    float a0 = 0.f, a1 = 0.f, a2 = 0.f, a3 = 0.f;
#pragma unroll
                    for (int l = 0; l < 64; l += 4) {
                        a0 = fmaf(wrow[l],     rlane(h2prev, l),     a0);
                        a1 = fmaf(wrow[l + 1], rlane(h2prev, l + 1), a1);
                        a2 = fmaf(wrow[l + 2], rlane(h2prev, l + 2), a2);
                        a3 = fmaf(wrow[l + 3], rlane(h2prev, l + 3), a3);
                    }
                    h2prev = tanh_fast(xv + ((a0 + a1) + (a2 + a3)));  // h2[s-2]
                }
            }
            BAR();
        }
        if (wv <= 1 && g < 63) {
#pragma unroll
            for (int j = 0; j < 8; ++j) xr[j] = xrn[j];
        }
    }

    // tail s = 513: wave2 makes xp2[512]; wave3 makes h2[511]
    {
        if (wv == 2) {
            float2 hh = *(const float2*)&h1buf[0][2 * lane];   // H1[512]
            float a0 = b2, a1 = 0.f, a2 = 0.f, a3 = 0.f;
#pragma unroll
            for (int l = 0; l < 64; l += 2) {
                float he0 = rlane(hh.x, l),     ho0 = rlane(hh.y, l);
                float he1 = rlane(hh.x, l + 1), ho1 = rlane(hh.y, l + 1);
                a0 = fmaf(wrow[2*l],     he0, a0);
                a1 = fmaf(wrow[2*l + 1], ho0, a1);
                a2 = fmaf(wrow[2*l + 2], he1, a2);
                a3 = fmaf(wrow[2*l + 3], ho1, a3);
            }
            xp2buf[0][lane] = (a0 + a1) + (a2 + a3);           // xp2[512]+bias
        } else if (wv == 3) {
            float xv = xp2buf[1][lane];                        // xp2[511]+bias
            float a0 = 0.f, a1 = 0.f, a2 = 0.f, a3 = 0.f;
#pragma unroll
            for (int l = 0; l < 64; l += 4) {
                a0 = fmaf(wrow[l],     rlane(h2prev, l),     a0);
                a1 = fmaf(wrow[l + 1], rlane(h2prev, l + 1), a1);
                a2 = fmaf(wrow[l + 2], rlane(h2prev, l + 2), a2);
                a3 = fmaf(wrow[l + 3], rlane(h2prev, l + 3), a3);
            }
            h2prev = tanh_fast(xv + ((a0 + a1) + (a2 + a3)));  // h2[511]
        }
        BAR();
    }
    // tail s = 514: wave3 makes h2[512]; then FC head
    if (wv == 3) {
        float xv = xp2buf[0][lane];                            // xp2[512]+bias
        float a0 = 0.f, a1 = 0.f, a2 = 0.f, a3 = 0.f;
#pragma unroll
        for (int l = 0; l < 64; l += 4) {
            a0 = fmaf(wrow[l],     rlane(h2prev, l),     a0);
            a1 = fmaf(wrow[l + 1], rlane(h2prev, l + 1), a1);
            a2 = fmaf(wrow[l + 2], rlane(h2prev, l + 2), a2);
            a3 = fmaf(wrow[l + 3], rlane(h2prev, l + 3), a3);
        }
        h2prev = tanh_fast(xv + ((a0 + a1) + (a2 + a3)));      // H2[512]

        float wfc[64];
        const int fr = lane & 31;
        const float4* fsrc = (const float4*)(Wfc1 + (size_t)fr * NH2);
#pragma unroll
        for (int i = 0; i < 16; ++i) {
            float4 v = fsrc[i];
            wfc[4*i+0] = v.x; wfc[4*i+1] = v.y;
            wfc[4*i+2] = v.z; wfc[4*i+3] = v.w;
        }
        float a = (lane < 32) ? bfc1[lane] : 0.0f;
#pragma unroll
        for (int k = 0; k < 64; ++k)
            a = fmaf(wfc[k], rlane(h2prev, k), a);
        float v = (lane < 32) ? fmaxf(a, 0.0f) * Wfc2[lane] : 0.0f;
#pragma unroll
        for (int off = 16; off > 0; off >>= 1) v += __shfl_down(v, off);
        if (lane == 0) out[b] = v + bfc2[0];
    }
}

extern "C" void kernel_launch(void* const* d_in, const int* in_sizes, int n_in,
                              void* d_out, int out_size, void* d_ws, size_t ws_size,
                              hipStream_t stream) {
    const float* x     = (const float*)d_in[0];
    const float* Wih1  = (const float*)d_in[1];
    const float* Whh1  = (const float*)d_in[2];
    const float* bih1  = (const float*)d_in[3];
    const float* bhh1  = (const float*)d_in[4];
    const float* Wih2  = (const float*)d_in[5];
    const float* Whh2  = (const float*)d_in[6];
    const float* bih2  = (const float*)d_in[7];
    const float* bhh2  = (const float*)d_in[8];
    const float* Wfc1  = (const float*)d_in[9];
    const float* bfc1  = (const float*)d_in[10];
    const float* Wfc2  = (const float*)d_in[11];
    const float* bfc2  = (const float*)d_in[12];
    float* outp = (float*)d_out;

    float* xp1 = (float*)d_ws;   // 32768 x 128 fp32 = 16 MB

    xp1_gemm<<<dim3((NB * TT) / 128), dim3(256), 0, stream>>>(x, Wih1, bih1, bhh1, xp1);
    rnn_scan<<<dim3(NB), dim3(256), 0, stream>>>(xp1, Whh1, Wih2, Whh2, bih2, bhh2,
                                                 Wfc1, bfc1, Wfc2, bfc2, outp);
}